// Round 1
// baseline (1280.478 us; speedup 1.0000x reference)
//
#include <hip/hip_runtime.h>

// CrossModalAttentionScorer — round 1: all-fp32, factorized.
// B=16, R=1024, T=512, D=H=1024.
//
// Algebra:
//   scores[b,r,t] = region[b,r]^T (Wr Wq^T) q[b,t]  + region.(Wr bq) + q[b,t].(Wq br) + br.bq
//   The per-row (t-constant) terms vanish under softmax -> only c[b,t]=q.(Wq br) kept.
//   out[b,r] = region.Ws0 + sum_t attn[t]*h[t] + bs,
//     h[b,r,t] = q[b,t] . (Ws1 + region[b,r]*Ws2)   (avoids materializing `attended`)
//
// Precision note: logits std ~= 32, temperature 1 => near-argmax softmax; everything
// upstream of softmax stays fp32 (bf16 there would flip near-tied rows past threshold).

#define BD 16
#define RD 1024
#define TD 512
#define DD 1024
#define HD 1024

__device__ __forceinline__ float wave_sum(float v) {
#pragma unroll
  for (int off = 32; off > 0; off >>= 1) v += __shfl_down(v, off);
  return v;
}
__device__ __forceinline__ float wave_max(float v) {
#pragma unroll
  for (int off = 32; off > 0; off >>= 1) v = fmaxf(v, __shfl_down(v, off));
  return v;
}

// C[M,N] = A[M,K] @ B[N,K]^T  (both row-major), batched via blockIdx.z.
// Optional: per-column add (colAdd[b*N+n]) and A-transform A' = w1[k] + A*w2[k].
// 64x64 tile, BK=16, 256 threads, 4x4 accum/thread.
__global__ __launch_bounds__(256) void gemm_nt(
    const float* __restrict__ A, const float* __restrict__ B, float* __restrict__ C,
    int Mm, int Nn, int Kk, long sA, long sB, long sC,
    const float* __restrict__ colAdd,
    const float* __restrict__ w1, const float* __restrict__ w2) {
  const int b = blockIdx.z;
  A += (long)b * sA;
  B += (long)b * sB;
  C += (long)b * sC;
  const float* cAdd = colAdd ? colAdd + (long)b * Nn : nullptr;

  const int m0 = blockIdx.y * 64, n0 = blockIdx.x * 64;
  __shared__ float As[16][68];  // [k][m], pad keeps float4 rows 16B-aligned, 2-way-max banks
  __shared__ float Bs[16][68];  // [k][n]
  const int tid = threadIdx.x;
  const int lrow = tid >> 2, lc4 = (tid & 3) * 4;  // staging: 64 rows x 4 float4
  const int tx = tid & 15, ty = tid >> 4;          // compute: 16x16 threads
  float acc[4][4] = {};

  for (int k0 = 0; k0 < Kk; k0 += 16) {
    float4 av = *(const float4*)&A[(long)(m0 + lrow) * Kk + k0 + lc4];
    if (w1) {
      const float4 a1 = *(const float4*)&w1[k0 + lc4];
      const float4 a2 = *(const float4*)&w2[k0 + lc4];
      av.x = a1.x + av.x * a2.x;
      av.y = a1.y + av.y * a2.y;
      av.z = a1.z + av.z * a2.z;
      av.w = a1.w + av.w * a2.w;
    }
    const float4 bv = *(const float4*)&B[(long)(n0 + lrow) * Kk + k0 + lc4];
    __syncthreads();
    As[lc4 + 0][lrow] = av.x;
    As[lc4 + 1][lrow] = av.y;
    As[lc4 + 2][lrow] = av.z;
    As[lc4 + 3][lrow] = av.w;
    Bs[lc4 + 0][lrow] = bv.x;
    Bs[lc4 + 1][lrow] = bv.y;
    Bs[lc4 + 2][lrow] = bv.z;
    Bs[lc4 + 3][lrow] = bv.w;
    __syncthreads();
#pragma unroll
    for (int kk = 0; kk < 16; ++kk) {
      const float4 a4 = *(const float4*)&As[kk][ty * 4];
      const float4 b4 = *(const float4*)&Bs[kk][tx * 4];
      acc[0][0] += a4.x * b4.x; acc[0][1] += a4.x * b4.y; acc[0][2] += a4.x * b4.z; acc[0][3] += a4.x * b4.w;
      acc[1][0] += a4.y * b4.x; acc[1][1] += a4.y * b4.y; acc[1][2] += a4.y * b4.z; acc[1][3] += a4.y * b4.w;
      acc[2][0] += a4.z * b4.x; acc[2][1] += a4.z * b4.y; acc[2][2] += a4.z * b4.z; acc[2][3] += a4.z * b4.w;
      acc[3][0] += a4.w * b4.x; acc[3][1] += a4.w * b4.y; acc[3][2] += a4.w * b4.z; acc[3][3] += a4.w * b4.w;
    }
  }
  float4 ca = make_float4(0.f, 0.f, 0.f, 0.f);
  if (cAdd) ca = *(const float4*)&cAdd[n0 + tx * 4];
#pragma unroll
  for (int i = 0; i < 4; ++i) {
    float4 o;
    o.x = acc[i][0] + ca.x;
    o.y = acc[i][1] + ca.y;
    o.z = acc[i][2] + ca.z;
    o.w = acc[i][3] + ca.w;
    *(float4*)&C[(long)(m0 + ty * 4 + i) * Nn + n0 + tx * 4] = o;
  }
}

// C[M,N] = A[M,K] @ B[K,N]  (row-major), single batch.
__global__ __launch_bounds__(256) void gemm_nn(
    const float* __restrict__ A, const float* __restrict__ B, float* __restrict__ C,
    int Mm, int Nn, int Kk) {
  const int m0 = blockIdx.y * 64, n0 = blockIdx.x * 64;
  __shared__ float As[16][68];  // [k][m]
  __shared__ float Bs[16][68];  // [k][n]
  const int tid = threadIdx.x;
  const int lrow = tid >> 2, lc4 = (tid & 3) * 4;   // A staging
  const int brow = tid >> 4, bc4 = (tid & 15) * 4;  // B staging: 16 rows x 16 float4
  const int tx = tid & 15, ty = tid >> 4;
  float acc[4][4] = {};

  for (int k0 = 0; k0 < Kk; k0 += 16) {
    const float4 av = *(const float4*)&A[(long)(m0 + lrow) * Kk + k0 + lc4];
    const float4 bv = *(const float4*)&B[(long)(k0 + brow) * Nn + n0 + bc4];
    __syncthreads();
    As[lc4 + 0][lrow] = av.x;
    As[lc4 + 1][lrow] = av.y;
    As[lc4 + 2][lrow] = av.z;
    As[lc4 + 3][lrow] = av.w;
    *(float4*)&Bs[brow][bc4] = bv;
    __syncthreads();
#pragma unroll
    for (int kk = 0; kk < 16; ++kk) {
      const float4 a4 = *(const float4*)&As[kk][ty * 4];
      const float4 b4 = *(const float4*)&Bs[kk][tx * 4];
      acc[0][0] += a4.x * b4.x; acc[0][1] += a4.x * b4.y; acc[0][2] += a4.x * b4.z; acc[0][3] += a4.x * b4.w;
      acc[1][0] += a4.y * b4.x; acc[1][1] += a4.y * b4.y; acc[1][2] += a4.y * b4.z; acc[1][3] += a4.y * b4.w;
      acc[2][0] += a4.z * b4.x; acc[2][1] += a4.z * b4.y; acc[2][2] += a4.z * b4.z; acc[2][3] += a4.z * b4.w;
      acc[3][0] += a4.w * b4.x; acc[3][1] += a4.w * b4.y; acc[3][2] += a4.w * b4.z; acc[3][3] += a4.w * b4.w;
    }
  }
#pragma unroll
  for (int i = 0; i < 4; ++i) {
    float4 o;
    o.x = acc[i][0];
    o.y = acc[i][1];
    o.z = acc[i][2];
    o.w = acc[i][3];
    *(float4*)&C[(long)(m0 + ty * 4 + i) * Nn + n0 + tx * 4] = o;
  }
}

// outv[row] = X[row,:] . v  — one wave per row, 4 rows per 256-thread block.
__global__ __launch_bounds__(256) void rowdot(
    const float* __restrict__ X, const float* __restrict__ v,
    float* __restrict__ outv, int Kk) {
  const int row = blockIdx.x * 4 + (threadIdx.x >> 6);
  const int lane = threadIdx.x & 63;
  const float* x = X + (long)row * Kk;
  float s = 0.f;
  for (int k = lane; k < Kk; k += 64) s += x[k] * v[k];
  s = wave_sum(s);
  if (lane == 0) outv[row] = s;
}

// Per (b,r) row: softmax over T logits, dot with h, add region.Ws0 + bs.
__global__ __launch_bounds__(256) void softmax_out(
    const float* __restrict__ S, const float* __restrict__ Hh,
    const float* __restrict__ region, const float* __restrict__ Ws,
    const float* __restrict__ bs, float* __restrict__ out) {
  const long row = blockIdx.x;  // b*R + r
  const float* s = S + row * TD;
  const float* h = Hh + row * TD;
  const float* rg = region + row * DD;
  const int tid = threadIdx.x, lane = tid & 63, wid = tid >> 6;

  const float s0 = s[tid], s1 = s[tid + 256];
  float m = fmaxf(s0, s1);
  m = wave_max(m);
  __shared__ float sm[4];
  if (lane == 0) sm[wid] = m;
  __syncthreads();
  m = fmaxf(fmaxf(sm[0], sm[1]), fmaxf(sm[2], sm[3]));

  const float e0 = __expf(s0 - m), e1 = __expf(s1 - m);
  float se = e0 + e1;
  float sh = e0 * h[tid] + e1 * h[tid + 256];
  float rd = 0.f;
#pragma unroll
  for (int i = 0; i < 4; ++i) {
    const int d = tid + i * 256;
    rd += rg[d] * Ws[d];
  }
  se = wave_sum(se);
  sh = wave_sum(sh);
  rd = wave_sum(rd);
  __shared__ float s3[3][4];
  if (lane == 0) {
    s3[0][wid] = se;
    s3[1][wid] = sh;
    s3[2][wid] = rd;
  }
  __syncthreads();
  if (tid == 0) {
    const float SE = s3[0][0] + s3[0][1] + s3[0][2] + s3[0][3];
    const float SH = s3[1][0] + s3[1][1] + s3[1][2] + s3[1][3];
    const float RDt = s3[2][0] + s3[2][1] + s3[2][2] + s3[2][3];
    out[row] = SH / SE + RDt + bs[0];
  }
}

extern "C" void kernel_launch(void* const* d_in, const int* in_sizes, int n_in,
                              void* d_out, int out_size, void* d_ws, size_t ws_size,
                              hipStream_t stream) {
  const float* region = (const float*)d_in[0];  // [B,R,D]
  const float* query  = (const float*)d_in[1];  // [B,T,D]
  const float* Wr     = (const float*)d_in[2];  // [D,H]
  const float* br     = (const float*)d_in[3];  // [H]
  const float* Wq     = (const float*)d_in[4];  // [D,H]
  // d_in[5] = bq: adds a t-constant per row -> cancels in softmax; unused.
  const float* Ws     = (const float*)d_in[6];  // [3D]
  const float* bs     = (const float*)d_in[7];  // [1]
  float* out = (float*)d_out;                   // [B*R]

  // Workspace layout (floats): M 1M | P 16M | S 8M | wqbr 1K | cvec 8K  (~100 MB)
  float* Mbuf = (float*)d_ws;
  float* P    = Mbuf + (1u << 20);
  float* S    = P + (16u << 20);
  float* Hh   = P;  // alias: P dead once S is written; gemm h doesn't read P
  float* wqbr = S + (8u << 20);
  float* cvec = wqbr + 1024;

  // M = Wr @ Wq^T   [D,D]
  gemm_nt<<<dim3(16, 16, 1), 256, 0, stream>>>(Wr, Wq, Mbuf, DD, DD, HD, 0, 0, 0,
                                               nullptr, nullptr, nullptr);
  // wqbr = Wq @ br  [D]
  rowdot<<<dim3(DD / 4), 256, 0, stream>>>(Wq, br, wqbr, HD);
  // cvec[b*T+t] = q[b,t] . wqbr
  rowdot<<<dim3(BD * TD / 4), 256, 0, stream>>>(query, wqbr, cvec, DD);
  // P = region_flat @ M   [B*R, D]
  gemm_nn<<<dim3(DD / 64, BD * RD / 64, 1), 256, 0, stream>>>(region, Mbuf, P,
                                                              BD * RD, DD, DD);
  // S[b] = P[b] @ q[b]^T + cvec[b,:]   [R,T] per batch
  gemm_nt<<<dim3(TD / 64, RD / 64, BD), 256, 0, stream>>>(
      P, query, S, RD, TD, DD, (long)RD * DD, (long)TD * DD, (long)RD * TD,
      cvec, nullptr, nullptr);
  // H[b] = (Ws1 + region[b]*Ws2) @ q[b]^T   [R,T] per batch
  gemm_nt<<<dim3(TD / 64, RD / 64, BD), 256, 0, stream>>>(
      region, query, Hh, RD, TD, DD, (long)RD * DD, (long)TD * DD, (long)RD * TD,
      nullptr, Ws + DD, Ws + 2 * DD);
  // out[b,r] = softmax(S).H + region.Ws0 + bs
  softmax_out<<<dim3(BD * RD), 256, 0, stream>>>(S, Hh, region, Ws, bs, out);
}

// Round 2
// 336.745 us; speedup vs baseline: 3.8025x; 3.8025x over previous
//
#include <hip/hip_runtime.h>

// CrossModalAttentionScorer — round 2: fp16 MFMA (m97-style 128x128 NT GEMM).
// B=16, R=1024, T=512, D=H=1024.
//
// Algebra (verified fp32 in round 1, absmax 0.0078):
//   softmax-relevant scores: S[b,r,t] = region[b,r] . Mt[t-side] . q  + cvec[b,t]
//     Mt = Wq @ Wr^T  (so P = NT(region, Mt), S = NT(P, q)); cvec = q.(Wq br); bq cancels.
//   out[b,r] = region.Ws0 + (sum_t softmax(S)_t * h_t) + bs,
//     h = NT(a2, q),  a2[b,r,d] = Ws1[d] + region[b,r,d]*Ws2[d].
// Precision: fp16 inputs + fp32 MFMA accum -> logit err ~0.03 std; bf16 would fail.

#define BD 16
#define RD 1024
#define TD 512
#define DD 1024
#define HD 1024

typedef _Float16 half8 __attribute__((ext_vector_type(8)));
typedef _Float16 half4 __attribute__((ext_vector_type(4)));
typedef float floatx4 __attribute__((ext_vector_type(4)));

__device__ __forceinline__ float wave_sum(float v) {
#pragma unroll
  for (int off = 32; off > 0; off >>= 1) v += __shfl_down(v, off);
  return v;
}
__device__ __forceinline__ float wave_max(float v) {
#pragma unroll
  for (int off = 32; off > 0; off >>= 1) v = fmaxf(v, __shfl_down(v, off));
  return v;
}

// Async global->LDS, 16B per lane. LDS dest is wave-uniform base + lane*16.
__device__ __forceinline__ void g2l(const _Float16* g, _Float16* l) {
  __builtin_amdgcn_global_load_lds(
      (const __attribute__((address_space(1))) unsigned int*)g,
      (__attribute__((address_space(3))) unsigned int*)l, 16, 0, 0);
}

// C[M,N] = A[M,K] @ B[N,K]^T, fp16 in, fp32 accum. 128x128 tile, BK=32,
// 256 threads = 4 waves in 2x2; each wave 64x64 via 4x4 mfma_f32_16x16x32_f16.
// Batched via blockIdx.z. OUT_HALF: store fp16; else fp32 (+ optional colAdd).
template <bool OUT_HALF>
__global__ __launch_bounds__(256) void mfma_nt(
    const _Float16* __restrict__ A, const _Float16* __restrict__ B,
    void* __restrict__ Cv, int N, int K, long sA, long sB, long sC,
    const float* __restrict__ colAdd, int sAdd) {
  const int b = blockIdx.z;
  A += (long)b * sA;
  B += (long)b * sB;
  const int m0 = blockIdx.y * 128, n0 = blockIdx.x * 128;
  __shared__ __align__(16) _Float16 As[128 * 32];
  __shared__ __align__(16) _Float16 Bs[128 * 32];
  const int tid = threadIdx.x;
  const int lane = tid & 63, w = tid >> 6;
  const int wr = w >> 1, wc = w & 1;

  // Staging: wave w fills rows 32w..32w+31 (two 16-row chunks; 1KB/issue).
  const int srow = lane >> 2;        // 0..15
  const int scol = (lane & 3) * 8;   // halves (16B per lane)
  const _Float16* ga0 = A + (long)(m0 + 32 * w + srow) * K + scol;
  const _Float16* ga1 = ga0 + (long)16 * K;
  const _Float16* gb0 = B + (long)(n0 + 32 * w + srow) * K + scol;
  const _Float16* gb1 = gb0 + (long)16 * K;
  _Float16* la0 = As + (32 * w) * 32;
  _Float16* la1 = As + (32 * w + 16) * 32;
  _Float16* lb0 = Bs + (32 * w) * 32;
  _Float16* lb1 = Bs + (32 * w + 16) * 32;

  floatx4 acc[4][4] = {};
  const int fr = lane & 15;          // A/B fragment row (m or n within 16-tile)
  const int fk = (lane >> 4) * 8;    // fragment k offset

  for (int k0 = 0; k0 < K; k0 += 32) {
    __syncthreads();
    g2l(ga0 + k0, la0);
    g2l(ga1 + k0, la1);
    g2l(gb0 + k0, lb0);
    g2l(gb1 + k0, lb1);
    __syncthreads();
    half8 af[4], bf[4];
#pragma unroll
    for (int i = 0; i < 4; ++i)
      af[i] = *(const half8*)&As[(64 * wr + 16 * i + fr) * 32 + fk];
#pragma unroll
    for (int j = 0; j < 4; ++j)
      bf[j] = *(const half8*)&Bs[(64 * wc + 16 * j + fr) * 32 + fk];
#pragma unroll
    for (int i = 0; i < 4; ++i)
#pragma unroll
      for (int j = 0; j < 4; ++j)
        acc[i][j] = __builtin_amdgcn_mfma_f32_16x16x32_f16(af[i], bf[j], acc[i][j], 0, 0, 0);
  }

  // C/D layout: col = lane&15, row = (lane>>4)*4 + reg.
  const int cr = (lane >> 4) * 4, cc = lane & 15;
  if (OUT_HALF) {
    _Float16* C = (_Float16*)Cv + (long)b * sC;
#pragma unroll
    for (int i = 0; i < 4; ++i)
#pragma unroll
      for (int r = 0; r < 4; ++r)
#pragma unroll
        for (int j = 0; j < 4; ++j)
          C[(long)(m0 + 64 * wr + 16 * i + cr + r) * N + n0 + 64 * wc + 16 * j + cc] =
              (_Float16)acc[i][j][r];
  } else {
    float* C = (float*)Cv + (long)b * sC;
    float ca[4] = {0.f, 0.f, 0.f, 0.f};
    if (colAdd) {
#pragma unroll
      for (int j = 0; j < 4; ++j)
        ca[j] = colAdd[(long)b * sAdd + n0 + 64 * wc + 16 * j + cc];
    }
#pragma unroll
    for (int i = 0; i < 4; ++i)
#pragma unroll
      for (int r = 0; r < 4; ++r)
#pragma unroll
        for (int j = 0; j < 4; ++j)
          C[(long)(m0 + 64 * wr + 16 * i + cr + r) * N + n0 + 64 * wc + 16 * j + cc] =
              acc[i][j][r] + ca[j];
  }
}

// fp32 -> fp16 elementwise, 4/thread.
__global__ __launch_bounds__(256) void cvt_f2h(const float* __restrict__ in,
                                               _Float16* __restrict__ out) {
  const long i = ((long)blockIdx.x * 256 + threadIdx.x) * 4;
  const float4 v = *(const float4*)&in[i];
  half4 h = {(_Float16)v.x, (_Float16)v.y, (_Float16)v.z, (_Float16)v.w};
  *(half4*)&out[i] = h;
}

// region -> region16 and a2 = half(Ws1 + region*Ws2).
__global__ __launch_bounds__(256) void conv_region(
    const float* __restrict__ region, const float* __restrict__ Ws,
    _Float16* __restrict__ r16, _Float16* __restrict__ a2) {
  const long i = ((long)blockIdx.x * 256 + threadIdx.x) * 4;
  const int d = (int)(i & (DD - 1));
  const float4 v = *(const float4*)&region[i];
  const float4 w1 = *(const float4*)&Ws[DD + d];
  const float4 w2 = *(const float4*)&Ws[2 * DD + d];
  half4 h = {(_Float16)v.x, (_Float16)v.y, (_Float16)v.z, (_Float16)v.w};
  *(half4*)&r16[i] = h;
  half4 a = {(_Float16)(w1.x + v.x * w2.x), (_Float16)(w1.y + v.y * w2.y),
             (_Float16)(w1.z + v.z * w2.z), (_Float16)(w1.w + v.w * w2.w)};
  *(half4*)&a2[i] = a;
}

// outv[row] = X[row,:] . v  — one wave per row, 4 rows/block (fp32, tiny).
__global__ __launch_bounds__(256) void rowdot(const float* __restrict__ X,
                                              const float* __restrict__ v,
                                              float* __restrict__ outv, int Kk) {
  const int row = blockIdx.x * 4 + (threadIdx.x >> 6);
  const int lane = threadIdx.x & 63;
  const float* x = X + (long)row * Kk;
  float s = 0.f;
  for (int k = lane; k < Kk; k += 64) s += x[k] * v[k];
  s = wave_sum(s);
  if (lane == 0) outv[row] = s;
}

// Per (b,r) row: softmax over T logits (fp32 S), dot with fp16 h, + region.Ws0 + bs.
__global__ __launch_bounds__(256) void softmax_out(
    const float* __restrict__ S, const _Float16* __restrict__ Hh,
    const float* __restrict__ region, const float* __restrict__ Ws,
    const float* __restrict__ bs, float* __restrict__ out) {
  const long row = blockIdx.x;  // b*R + r
  const float* s = S + row * TD;
  const _Float16* h = Hh + row * TD;
  const float* rg = region + row * DD;
  const int tid = threadIdx.x, lane = tid & 63, wid = tid >> 6;

  const float s0 = s[tid], s1 = s[tid + 256];
  float m = fmaxf(s0, s1);
  m = wave_max(m);
  __shared__ float sm[4];
  if (lane == 0) sm[wid] = m;
  __syncthreads();
  m = fmaxf(fmaxf(sm[0], sm[1]), fmaxf(sm[2], sm[3]));

  const float e0 = __expf(s0 - m), e1 = __expf(s1 - m);
  float se = e0 + e1;
  float sh = e0 * (float)h[tid] + e1 * (float)h[tid + 256];
  float rd = 0.f;
#pragma unroll
  for (int i = 0; i < 4; ++i) {
    const int d = tid + i * 256;
    rd += rg[d] * Ws[d];
  }
  se = wave_sum(se);
  sh = wave_sum(sh);
  rd = wave_sum(rd);
  __shared__ float s3[3][4];
  if (lane == 0) {
    s3[0][wid] = se;
    s3[1][wid] = sh;
    s3[2][wid] = rd;
  }
  __syncthreads();
  if (tid == 0) {
    const float SE = s3[0][0] + s3[0][1] + s3[0][2] + s3[0][3];
    const float SH = s3[1][0] + s3[1][1] + s3[1][2] + s3[1][3];
    const float RDt = s3[2][0] + s3[2][1] + s3[2][2] + s3[2][3];
    out[row] = SH / SE + RDt + bs[0];
  }
}

extern "C" void kernel_launch(void* const* d_in, const int* in_sizes, int n_in,
                              void* d_out, int out_size, void* d_ws, size_t ws_size,
                              hipStream_t stream) {
  const float* region = (const float*)d_in[0];
  const float* query  = (const float*)d_in[1];
  const float* Wr     = (const float*)d_in[2];
  const float* br     = (const float*)d_in[3];
  const float* Wq     = (const float*)d_in[4];
  // d_in[5] = bq: t-constant per row, cancels in softmax.
  const float* Ws     = (const float*)d_in[6];
  const float* bs     = (const float*)d_in[7];
  float* out = (float*)d_out;

  // ws layout (bytes). Aliasing: slot0 = region16 then S; slot1 = a2 then P16.
  char* p = (char*)d_ws;
  _Float16* region16 = (_Float16*)p;               // 32 MB (16M halves)
  float*    S        = (float*)p;                  // 32 MB (8M floats), after P done
  _Float16* a2       = (_Float16*)(p + (32u << 20));  // 32 MB
  _Float16* P16      = (_Float16*)(p + (32u << 20));  // 32 MB, after Hh done
  _Float16* query16  = (_Float16*)(p + (64u << 20));  // 16 MB
  _Float16* Hh       = (_Float16*)(p + (80u << 20));  // 16 MB
  _Float16* Wr16     = (_Float16*)(p + (96u << 20));  // 2 MB
  _Float16* Wq16     = (_Float16*)(p + (98u << 20));  // 2 MB
  _Float16* Mt16     = (_Float16*)(p + (100u << 20)); // 2 MB
  float*    wqbr     = (float*)(p + (102u << 20));    // 4 KB
  float*    cvec     = wqbr + 1024;                   // 32 KB

  // Conversions.
  cvt_f2h<<<dim3(1024), 256, 0, stream>>>(Wr, Wr16);
  cvt_f2h<<<dim3(1024), 256, 0, stream>>>(Wq, Wq16);
  cvt_f2h<<<dim3(8192), 256, 0, stream>>>(query, query16);
  conv_region<<<dim3(16384), 256, 0, stream>>>(region, Ws, region16, a2);

  // cvec[b,t] = q[b,t].(Wq br)  (fp32, tiny).
  rowdot<<<dim3(DD / 4), 256, 0, stream>>>(Wq, br, wqbr, HD);
  rowdot<<<dim3(BD * TD / 4), 256, 0, stream>>>(query, wqbr, cvec, DD);

  // Mt = Wq @ Wr^T   [D,D] fp16.
  mfma_nt<true><<<dim3(8, 8, 1), 256, 0, stream>>>(
      Wq16, Wr16, Mt16, DD, HD, 0, 0, 0, nullptr, 0);
  // Hh[b] = a2[b] @ q[b]^T   [R,T] fp16  (before P overwrites slot1!).
  mfma_nt<true><<<dim3(TD / 128, RD / 128, BD), 256, 0, stream>>>(
      a2, query16, Hh, TD, DD, (long)RD * DD, (long)TD * DD, (long)RD * TD,
      nullptr, 0);
  // P = region16 @ Mt^T   [B*R, D] fp16 (into slot1; a2 dead).
  mfma_nt<true><<<dim3(DD / 128, BD * RD / 128, 1), 256, 0, stream>>>(
      region16, Mt16, P16, DD, DD, 0, 0, 0, nullptr, 0);
  // S[b] = P[b] @ q[b]^T + cvec[b,:]   [R,T] fp32 (into slot0; region16 dead).
  mfma_nt<false><<<dim3(TD / 128, RD / 128, BD), 256, 0, stream>>>(
      P16, query16, S, TD, DD, (long)RD * DD, (long)TD * DD, (long)RD * TD,
      cvec, TD);
  // out = softmax(S).Hh + region.Ws0 + bs.
  softmax_out<<<dim3(BD * RD), 256, 0, stream>>>(S, Hh, region, Ws, bs, out);
}

// Round 3
// 302.857 us; speedup vs baseline: 4.2280x; 1.1119x over previous
//
#include <hip/hip_runtime.h>

// CrossModalAttentionScorer — round 3: re-associated score chain + LDS swizzle.
// B=16, R=1024, T=512, D=H=1024.
//
//   M2 = Wr @ Wq^T            [D,D]   (2.1 GF)
//   Qp = NT(query, M2)        [B*T,D] (17.2 GF)   <- replaces 34.4-GF P-GEMM
//   S  = NT(region, Qp)       [B,R,T] (17.2 GF, fp32 out)
//   Hh = NT(Ws1+region*Ws2, query) [B,R,T] (17.2 GF, A-transform fused in-frag)
//   out = softmax(S + cvec).Hh + region.Ws0 + bs   (cvec = q.(Wq br); bq cancels)
//
// LDS: chunk c (16B) of row r stored at slot c^((r>>1)&3) — kills the 4-way
// phase conflict seen in round 2 (SQ_LDS_BANK_CONFLICT 4.19M/dispatch).

#define BD 16
#define RD 1024
#define TD 512
#define DD 1024
#define HD 1024

typedef _Float16 half8 __attribute__((ext_vector_type(8)));
typedef _Float16 half4 __attribute__((ext_vector_type(4)));
typedef float floatx4 __attribute__((ext_vector_type(4)));

__device__ __forceinline__ float wave_sum(float v) {
#pragma unroll
  for (int off = 32; off > 0; off >>= 1) v += __shfl_down(v, off);
  return v;
}
__device__ __forceinline__ float wave_max(float v) {
#pragma unroll
  for (int off = 32; off > 0; off >>= 1) v = fmaxf(v, __shfl_down(v, off));
  return v;
}

// Async global->LDS, 16B/lane; LDS dest = wave-uniform base + lane*16.
__device__ __forceinline__ void g2l(const _Float16* g, _Float16* l) {
  __builtin_amdgcn_global_load_lds(
      (const __attribute__((address_space(1))) unsigned int*)g,
      (__attribute__((address_space(3))) unsigned int*)l, 16, 0, 0);
}

// C[M,N] = A'[M,K] @ B[N,K]^T, fp16 in / fp32 accum. 128x128 tile, BK=32,
// 4 waves (2x2), wave = 64x64 via 4x4 mfma_f32_16x16x32_f16. Batch = blockIdx.z.
// TRANS_A: A' = w1[k] + A*w2[k] applied on fragments (a2 never materialized).
template <bool OUT_HALF, bool TRANS_A>
__global__ __launch_bounds__(256) void mfma_nt(
    const _Float16* __restrict__ A, const _Float16* __restrict__ B,
    void* __restrict__ Cv, int N, int K, long sA, long sB, long sC,
    const _Float16* __restrict__ w1h, const _Float16* __restrict__ w2h) {
  const int b = blockIdx.z;
  A += (long)b * sA;
  B += (long)b * sB;
  const int m0 = blockIdx.y * 128, n0 = blockIdx.x * 128;
  __shared__ __align__(16) _Float16 As[128 * 32];
  __shared__ __align__(16) _Float16 Bs[128 * 32];
  const int tid = threadIdx.x;
  const int lane = tid & 63, w = tid >> 6;
  const int wr = w >> 1, wc = w & 1;

  // Staging: wave w fills rows 32w..32w+31 as two 16-row chunks. Lane L owns
  // LDS slot (row=L>>2, chunk=L&3); it loads global chunk (L&3)^((row>>1)&3).
  const int srow = lane >> 2;
  const int scol = ((lane & 3) ^ ((srow >> 1) & 3)) * 8;
  const _Float16* ga0 = A + (long)(m0 + 32 * w + srow) * K + scol;
  const _Float16* ga1 = ga0 + (long)16 * K;
  const _Float16* gb0 = B + (long)(n0 + 32 * w + srow) * K + scol;
  const _Float16* gb1 = gb0 + (long)16 * K;
  _Float16* la0 = As + (32 * w) * 32;
  _Float16* la1 = As + (32 * w + 16) * 32;
  _Float16* lb0 = Bs + (32 * w) * 32;
  _Float16* lb1 = Bs + (32 * w + 16) * 32;

  floatx4 acc[4][4] = {};
  const int fr = lane & 15;                       // fragment row within 16-tile
  const int g = lane >> 4;                        // global 8-half k-chunk
  const int fs = (g ^ ((fr >> 1) & 3)) * 8;       // swizzled LDS half-offset

  for (int k0 = 0; k0 < K; k0 += 32) {
    __syncthreads();
    g2l(ga0 + k0, la0);
    g2l(ga1 + k0, la1);
    g2l(gb0 + k0, lb0);
    g2l(gb1 + k0, lb1);
    __syncthreads();
    half8 w1f, w2f;
    if (TRANS_A) {
      w1f = *(const half8*)&w1h[k0 + g * 8];
      w2f = *(const half8*)&w2h[k0 + g * 8];
    }
    half8 af[4], bf[4];
#pragma unroll
    for (int i = 0; i < 4; ++i) {
      af[i] = *(const half8*)&As[(64 * wr + 16 * i + fr) * 32 + fs];
      if (TRANS_A) af[i] = w1f + af[i] * w2f;
    }
#pragma unroll
    for (int j = 0; j < 4; ++j)
      bf[j] = *(const half8*)&Bs[(64 * wc + 16 * j + fr) * 32 + fs];
#pragma unroll
    for (int i = 0; i < 4; ++i)
#pragma unroll
      for (int j = 0; j < 4; ++j)
        acc[i][j] = __builtin_amdgcn_mfma_f32_16x16x32_f16(af[i], bf[j], acc[i][j], 0, 0, 0);
  }

  // C/D layout: col = lane&15, row = (lane>>4)*4 + reg.
  const int cr = (lane >> 4) * 4, cc = lane & 15;
  if (OUT_HALF) {
    _Float16* C = (_Float16*)Cv + (long)b * sC;
#pragma unroll
    for (int i = 0; i < 4; ++i)
#pragma unroll
      for (int r = 0; r < 4; ++r)
#pragma unroll
        for (int j = 0; j < 4; ++j)
          C[(long)(m0 + 64 * wr + 16 * i + cr + r) * N + n0 + 64 * wc + 16 * j + cc] =
              (_Float16)acc[i][j][r];
  } else {
    float* C = (float*)Cv + (long)b * sC;
#pragma unroll
    for (int i = 0; i < 4; ++i)
#pragma unroll
      for (int r = 0; r < 4; ++r)
#pragma unroll
        for (int j = 0; j < 4; ++j)
          C[(long)(m0 + 64 * wr + 16 * i + cr + r) * N + n0 + 64 * wc + 16 * j + cc] =
              acc[i][j][r];
  }
}

// fp32 -> fp16 elementwise, 4/thread.
__global__ __launch_bounds__(256) void cvt_f2h(const float* __restrict__ in,
                                               _Float16* __restrict__ out) {
  const long i = ((long)blockIdx.x * 256 + threadIdx.x) * 4;
  const float4 v = *(const float4*)&in[i];
  half4 h = {(_Float16)v.x, (_Float16)v.y, (_Float16)v.z, (_Float16)v.w};
  *(half4*)&out[i] = h;
}

// One block per (b,r) row: region -> region16, and rdvec[row] = region.Ws0.
__global__ __launch_bounds__(256) void conv_region(
    const float* __restrict__ region, const float* __restrict__ Ws,
    _Float16* __restrict__ r16, float* __restrict__ rdvec) {
  const long row = blockIdx.x;
  const int tid = threadIdx.x, lane = tid & 63, wid = tid >> 6;
  const long i = row * DD + tid * 4;
  const float4 v = *(const float4*)&region[i];
  half4 h = {(_Float16)v.x, (_Float16)v.y, (_Float16)v.z, (_Float16)v.w};
  *(half4*)&r16[i] = h;
  const float4 w0 = *(const float4*)&Ws[tid * 4];
  float rd = v.x * w0.x + v.y * w0.y + v.z * w0.z + v.w * w0.w;
  rd = wave_sum(rd);
  __shared__ float sm[4];
  if (lane == 0) sm[wid] = rd;
  __syncthreads();
  if (tid == 0) rdvec[row] = sm[0] + sm[1] + sm[2] + sm[3];
}

// One block per (b,t) row: query -> query16, and cvec[row] = q.(Wq br).
__global__ __launch_bounds__(256) void conv_query(
    const float* __restrict__ query, const float* __restrict__ wqbr,
    _Float16* __restrict__ q16, float* __restrict__ cvec) {
  const long row = blockIdx.x;
  const int tid = threadIdx.x, lane = tid & 63, wid = tid >> 6;
  const long i = row * DD + tid * 4;
  const float4 v = *(const float4*)&query[i];
  half4 h = {(_Float16)v.x, (_Float16)v.y, (_Float16)v.z, (_Float16)v.w};
  *(half4*)&q16[i] = h;
  const float4 w = *(const float4*)&wqbr[tid * 4];
  float c = v.x * w.x + v.y * w.y + v.z * w.z + v.w * w.w;
  c = wave_sum(c);
  __shared__ float sm[4];
  if (lane == 0) sm[wid] = c;
  __syncthreads();
  if (tid == 0) cvec[row] = sm[0] + sm[1] + sm[2] + sm[3];
}

// outv[row] = X[row,:] . v  (fp32, tiny; used for wqbr = Wq @ br).
__global__ __launch_bounds__(256) void rowdot(const float* __restrict__ X,
                                              const float* __restrict__ v,
                                              float* __restrict__ outv, int Kk) {
  const int row = blockIdx.x * 4 + (threadIdx.x >> 6);
  const int lane = threadIdx.x & 63;
  const float* x = X + (long)row * Kk;
  float s = 0.f;
  for (int k = lane; k < Kk; k += 64) s += x[k] * v[k];
  s = wave_sum(s);
  if (lane == 0) outv[row] = s;
}

// Per (b,r) row: softmax over T logits (S + cvec), dot fp16 h, + rdvec + bs.
__global__ __launch_bounds__(256) void softmax_out(
    const float* __restrict__ S, const _Float16* __restrict__ Hh,
    const float* __restrict__ cvec, const float* __restrict__ rdvec,
    const float* __restrict__ bs, float* __restrict__ out) {
  const long row = blockIdx.x;  // b*R + r
  const int b = (int)(row >> 10);
  const float* s = S + row * TD;
  const _Float16* h = Hh + row * TD;
  const float* cv = cvec + (long)b * TD;
  const int tid = threadIdx.x, lane = tid & 63, wid = tid >> 6;

  const float s0 = s[tid] + cv[tid], s1 = s[tid + 256] + cv[tid + 256];
  float m = fmaxf(s0, s1);
  m = wave_max(m);
  __shared__ float sm[4];
  if (lane == 0) sm[wid] = m;
  __syncthreads();
  m = fmaxf(fmaxf(sm[0], sm[1]), fmaxf(sm[2], sm[3]));

  const float e0 = __expf(s0 - m), e1 = __expf(s1 - m);
  float se = e0 + e1;
  float sh = e0 * (float)h[tid] + e1 * (float)h[tid + 256];
  se = wave_sum(se);
  sh = wave_sum(sh);
  __shared__ float s2[2][4];
  if (lane == 0) {
    s2[0][wid] = se;
    s2[1][wid] = sh;
  }
  __syncthreads();
  if (tid == 0) {
    const float SE = s2[0][0] + s2[0][1] + s2[0][2] + s2[0][3];
    const float SH = s2[1][0] + s2[1][1] + s2[1][2] + s2[1][3];
    out[row] = SH / SE + rdvec[row] + bs[0];
  }
}

extern "C" void kernel_launch(void* const* d_in, const int* in_sizes, int n_in,
                              void* d_out, int out_size, void* d_ws, size_t ws_size,
                              hipStream_t stream) {
  const float* region = (const float*)d_in[0];
  const float* query  = (const float*)d_in[1];
  const float* Wr     = (const float*)d_in[2];
  const float* br     = (const float*)d_in[3];
  const float* Wq     = (const float*)d_in[4];
  // d_in[5] = bq: t-constant per score row, cancels in softmax.
  const float* Ws     = (const float*)d_in[6];
  const float* bs     = (const float*)d_in[7];
  float* out = (float*)d_out;

  // ws layout (MiB offsets), total ~102 MiB (round-2 footprint, known safe).
  // Qp and Hh share a slot: Hh GEMM runs after S GEMM (last reader of Qp).
  char* p = (char*)d_ws;
  _Float16* region16 = (_Float16*)p;                  // 32 MiB
  float*    S        = (float*)(p + (32u << 20));     // 32 MiB
  _Float16* query16  = (_Float16*)(p + (64u << 20));  // 16 MiB
  _Float16* Qp       = (_Float16*)(p + (80u << 20));  // 16 MiB
  _Float16* Hh       = Qp;                            // alias (see order)
  _Float16* Wr16     = (_Float16*)(p + (96u << 20));  // 2 MiB
  _Float16* Wq16     = (_Float16*)(p + (98u << 20));  // 2 MiB
  _Float16* M2       = (_Float16*)(p + (100u << 20)); // 2 MiB
  _Float16* Ws16     = (_Float16*)(p + (102u << 20)); // 4 KiB (Ws1|Ws2)
  float*    wqbr     = (float*)(p + (102u << 20) + 8192);
  float*    cvec     = wqbr + 1024;
  float*    rdvec    = cvec + BD * TD;

  cvt_f2h<<<dim3(1024), 256, 0, stream>>>(Wr, Wr16);
  cvt_f2h<<<dim3(1024), 256, 0, stream>>>(Wq, Wq16);
  cvt_f2h<<<dim3(2), 256, 0, stream>>>(Ws + DD, Ws16);
  rowdot<<<dim3(DD / 4), 256, 0, stream>>>(Wq, br, wqbr, HD);
  conv_region<<<dim3(BD * RD), 256, 0, stream>>>(region, Ws, region16, rdvec);
  conv_query<<<dim3(BD * TD), 256, 0, stream>>>(query, wqbr, query16, cvec);

  // M2 = Wr @ Wq^T  [D,D] fp16.
  mfma_nt<true, false><<<dim3(8, 8, 1), 256, 0, stream>>>(
      Wr16, Wq16, M2, DD, HD, 0, 0, 0, nullptr, nullptr);
  // Qp = query @ M2^T  [B*T, D] fp16.
  mfma_nt<true, false><<<dim3(DD / 128, BD * TD / 128, 1), 256, 0, stream>>>(
      query16, M2, Qp, DD, DD, 0, 0, 0, nullptr, nullptr);
  // S[b] = region[b] @ Qp[b]^T  [R,T] fp32.
  mfma_nt<false, false><<<dim3(TD / 128, RD / 128, BD), 256, 0, stream>>>(
      region16, Qp, S, TD, DD, (long)RD * DD, (long)TD * DD, (long)RD * TD,
      nullptr, nullptr);
  // Hh[b] = (Ws1 + region[b]*Ws2) @ query[b]^T  [R,T] fp16 (overwrites Qp).
  mfma_nt<true, true><<<dim3(TD / 128, RD / 128, BD), 256, 0, stream>>>(
      region16, query16, Hh, TD, DD, (long)RD * DD, (long)TD * DD, (long)RD * TD,
      Ws16, Ws16 + DD);
  // out = softmax(S + cvec).Hh + region.Ws0 + bs.
  softmax_out<<<dim3(BD * RD), 256, 0, stream>>>(S, Hh, cvec, rdvec, bs, out);
}

// Round 4
// 259.401 us; speedup vs baseline: 4.9363x; 1.1675x over previous
//
#include <hip/hip_runtime.h>

// CrossModalAttentionScorer — round 4: pipelined K-loop (reg-prefetch + LDS
// double-buffer, 1 barrier/iter) + fused S/H GEMM with split-softmax epilogue.
// B=16, R=1024, T=512, D=H=1024.
//
//   M2 = Wr @ Wq^T; Qp = NT(query, M2); cvec = q.(Wq br); bq cancels in softmax.
//   Fused kernel, per (b, r-tile, t-tile):
//     accS = NT(region, Qp) (+cvec), accH = NT(Ws1+region*Ws2, query)
//     -> per-wave 64-col chunk stats (rowmax M, L=sum e^{s-M}, HS=sum e^{s-M} h)
//   combine: out = (sum HS_c e^{M_c-GM}) / (sum L_c e^{M_c-GM}) + region.Ws0 + bs
//
// Round-3 lesson: global_load_lds => vmcnt(0) drain at every barrier; at
// 2 blocks/CU (512-block grids) that is ~90% stall. Prefetch-to-regs gives the
// loads a full iteration in flight.

#define BD 16
#define RD 1024
#define TD 512
#define DD 1024
#define BR (BD * RD)

typedef _Float16 half8 __attribute__((ext_vector_type(8)));
typedef _Float16 half4 __attribute__((ext_vector_type(4)));
typedef float floatx4 __attribute__((ext_vector_type(4)));

__device__ __forceinline__ float wave_sum(float v) {
#pragma unroll
  for (int off = 32; off > 0; off >>= 1) v += __shfl_down(v, off);
  return v;
}

// Pipelined 128x128x32 NT GEMM. FUSED: two B tiles (B0=Qp for scores,
// B1=query for H), split-softmax stats epilogue. !FUSED: fp16 C = A @ B0^T.
template <bool FUSED>
__global__ __launch_bounds__(256) void gemm_pipe(
    const _Float16* __restrict__ A, const _Float16* __restrict__ B0,
    const _Float16* __restrict__ B1, _Float16* __restrict__ C,
    float* __restrict__ Ms, float* __restrict__ Ls, float* __restrict__ Hs,
    const float* __restrict__ cvec, const _Float16* __restrict__ wsh,
    int N, int K, long sA, long sB, long sC) {
  constexpr int TT = FUSED ? 3 : 2;           // tiles per buffer
  __shared__ __align__(16) _Float16 lds[2 * TT * 4096];  // 48 or 32 KB
  __shared__ __align__(16) _Float16 wlds[FUSED ? 2048 : 16];

  const int b = blockIdx.z;
  A += (long)b * sA;
  B0 += (long)b * sB;
  if (FUSED) B1 += (long)b * sB;
  const int m0 = blockIdx.y * 128, n0 = blockIdx.x * 128;
  const int tid = threadIdx.x, lane = tid & 63, w = tid >> 6;
  const int wr = w >> 1, wc = w & 1;

  // Staging: wave w owns rows 32w..32w+31 of each tile (two 16-row chunks).
  // Lane L -> row srow, LDS slot (L&3); global chunk xor-swizzled (round-3
  // proven: 0 bank conflicts).
  const int srow = lane >> 2;
  const int slot = lane & 3;
  const int scol = (slot ^ ((srow >> 1) & 3)) * 8;
  const _Float16* gA = A + (long)(m0 + 32 * w + srow) * K + scol;
  const _Float16* gP = B0 + (long)(n0 + 32 * w + srow) * K + scol;
  const _Float16* gQ = FUSED ? B1 + (long)(n0 + 32 * w + srow) * K + scol : nullptr;
  const long rstep = (long)16 * K;
  const int wofs = (32 * w + srow) * 32 + slot * 8;  // halves within a tile

  if (FUSED) *(int4*)&wlds[tid * 8] = *(const int4*)&wsh[tid * 8];  // Ws1|Ws2

  const int NK = K / 32;
  int4 pA0, pA1, pP0, pP1, pQ0, pQ1;
  // tile 0 -> regs -> LDS buf 0
  pA0 = *(const int4*)gA;
  pA1 = *(const int4*)(gA + rstep);
  pP0 = *(const int4*)gP;
  pP1 = *(const int4*)(gP + rstep);
  if (FUSED) {
    pQ0 = *(const int4*)gQ;
    pQ1 = *(const int4*)(gQ + rstep);
  }
  *(int4*)&lds[wofs] = pA0;
  *(int4*)&lds[wofs + 512] = pA1;
  *(int4*)&lds[4096 + wofs] = pP0;
  *(int4*)&lds[4096 + wofs + 512] = pP1;
  if (FUSED) {
    *(int4*)&lds[8192 + wofs] = pQ0;
    *(int4*)&lds[8192 + wofs + 512] = pQ1;
  }
  // tile 1 -> regs
  if (NK > 1) {
    pA0 = *(const int4*)(gA + 32);
    pA1 = *(const int4*)(gA + rstep + 32);
    pP0 = *(const int4*)(gP + 32);
    pP1 = *(const int4*)(gP + rstep + 32);
    if (FUSED) {
      pQ0 = *(const int4*)(gQ + 32);
      pQ1 = *(const int4*)(gQ + rstep + 32);
    }
  }
  __syncthreads();

  floatx4 accS[4][4] = {};
  floatx4 accH[4][4] = {};  // dead-stripped when !FUSED
  const int fr = lane & 15, g = lane >> 4;
  const int fs = (g ^ ((fr >> 1) & 3)) * 8;

  for (int kt = 0; kt < NK; ++kt) {
    const int cur = (kt & 1) * TT * 4096;
    const int nxt = ((kt + 1) & 1) * TT * 4096;
    if (kt + 1 < NK) {  // stage tile kt+1 (regs -> LDS buf nxt)
      *(int4*)&lds[nxt + wofs] = pA0;
      *(int4*)&lds[nxt + wofs + 512] = pA1;
      *(int4*)&lds[nxt + 4096 + wofs] = pP0;
      *(int4*)&lds[nxt + 4096 + wofs + 512] = pP1;
      if (FUSED) {
        *(int4*)&lds[nxt + 8192 + wofs] = pQ0;
        *(int4*)&lds[nxt + 8192 + wofs + 512] = pQ1;
      }
    }
    if (kt + 2 < NK) {  // prefetch tile kt+2 -> regs (a full iter in flight)
      const long go = (long)(kt + 2) * 32;
      pA0 = *(const int4*)(gA + go);
      pA1 = *(const int4*)(gA + rstep + go);
      pP0 = *(const int4*)(gP + go);
      pP1 = *(const int4*)(gP + rstep + go);
      if (FUSED) {
        pQ0 = *(const int4*)(gQ + go);
        pQ1 = *(const int4*)(gQ + rstep + go);
      }
    }
    half8 af[4], bp[4], bq[4], w1f, w2f;
#pragma unroll
    for (int i = 0; i < 4; ++i)
      af[i] = *(const half8*)&lds[cur + (64 * wr + 16 * i + fr) * 32 + fs];
#pragma unroll
    for (int j = 0; j < 4; ++j)
      bp[j] = *(const half8*)&lds[cur + 4096 + (64 * wc + 16 * j + fr) * 32 + fs];
    if (FUSED) {
#pragma unroll
      for (int j = 0; j < 4; ++j)
        bq[j] = *(const half8*)&lds[cur + 8192 + (64 * wc + 16 * j + fr) * 32 + fs];
      w1f = *(const half8*)&wlds[kt * 32 + g * 8];
      w2f = *(const half8*)&wlds[1024 + kt * 32 + g * 8];
    }
#pragma unroll
    for (int i = 0; i < 4; ++i)
#pragma unroll
      for (int j = 0; j < 4; ++j)
        accS[i][j] = __builtin_amdgcn_mfma_f32_16x16x32_f16(af[i], bp[j], accS[i][j], 0, 0, 0);
    if (FUSED) {
#pragma unroll
      for (int i = 0; i < 4; ++i) af[i] = w1f + af[i] * w2f;  // A' for H
#pragma unroll
      for (int i = 0; i < 4; ++i)
#pragma unroll
        for (int j = 0; j < 4; ++j)
          accH[i][j] = __builtin_amdgcn_mfma_f32_16x16x32_f16(af[i], bq[j], accH[i][j], 0, 0, 0);
    }
    __syncthreads();
  }

  // C/D layout: col = lane&15 (=fr), row = (lane>>4)*4 + reg (=g*4+r).
  const int cr = g * 4, cc = fr;
  if (!FUSED) {
    _Float16* Cw = C + (long)b * sC;
#pragma unroll
    for (int i = 0; i < 4; ++i)
#pragma unroll
      for (int r = 0; r < 4; ++r)
#pragma unroll
        for (int j = 0; j < 4; ++j)
          Cw[(long)(m0 + 64 * wr + 16 * i + cr + r) * N + n0 + 64 * wc + 16 * j + cc] =
              (_Float16)accS[i][j][r];
  } else {
    float cv[4];
#pragma unroll
    for (int j = 0; j < 4; ++j)
      cv[j] = cvec[(long)b * TD + n0 + 64 * wc + 16 * j + cc];
    const int chunk = blockIdx.x * 2 + wc;  // 64-col chunk index 0..7
    const long rowBase = (long)b * RD + m0 + 64 * wr + cr;
#pragma unroll
    for (int i = 0; i < 4; ++i) {
#pragma unroll
      for (int r = 0; r < 4; ++r) {
        float mx = -1e30f;
#pragma unroll
        for (int j = 0; j < 4; ++j) mx = fmaxf(mx, accS[i][j][r] + cv[j]);
        mx = fmaxf(mx, __shfl_xor(mx, 1));
        mx = fmaxf(mx, __shfl_xor(mx, 2));
        mx = fmaxf(mx, __shfl_xor(mx, 4));
        mx = fmaxf(mx, __shfl_xor(mx, 8));
        float l = 0.f, hs = 0.f;
#pragma unroll
        for (int j = 0; j < 4; ++j) {
          const float e = __expf(accS[i][j][r] + cv[j] - mx);
          l += e;
          hs += e * accH[i][j][r];
        }
        l += __shfl_xor(l, 1); hs += __shfl_xor(hs, 1);
        l += __shfl_xor(l, 2); hs += __shfl_xor(hs, 2);
        l += __shfl_xor(l, 4); hs += __shfl_xor(hs, 4);
        l += __shfl_xor(l, 8); hs += __shfl_xor(hs, 8);
        if (cc == 0) {
          const long idx = (long)chunk * BR + rowBase + 16 * i + r;
          Ms[idx] = mx;
          Ls[idx] = l;
          Hs[idx] = hs;
        }
      }
    }
  }
}

// Combine 8 chunk-stats per row: out = HS/L + rdvec + bs.
__global__ __launch_bounds__(256) void combine(
    const float* __restrict__ Ms, const float* __restrict__ Ls,
    const float* __restrict__ Hs, const float* __restrict__ rdvec,
    const float* __restrict__ bs, float* __restrict__ out) {
  const int row = blockIdx.x * 256 + threadIdx.x;
  float mv[8];
  float gm = -1e30f;
#pragma unroll
  for (int c = 0; c < 8; ++c) {
    mv[c] = Ms[(long)c * BR + row];
    gm = fmaxf(gm, mv[c]);
  }
  float L = 0.f, HS = 0.f;
#pragma unroll
  for (int c = 0; c < 8; ++c) {
    const float s = __expf(mv[c] - gm);
    L += Ls[(long)c * BR + row] * s;
    HS += Hs[(long)c * BR + row] * s;
  }
  out[row] = HS / L + rdvec[row] + bs[0];
}

// fp32 -> fp16 elementwise, 4/thread.
__global__ __launch_bounds__(256) void cvt_f2h(const float* __restrict__ in,
                                               _Float16* __restrict__ out) {
  const long i = ((long)blockIdx.x * 256 + threadIdx.x) * 4;
  const float4 v = *(const float4*)&in[i];
  half4 h = {(_Float16)v.x, (_Float16)v.y, (_Float16)v.z, (_Float16)v.w};
  *(half4*)&out[i] = h;
}

// One block per (b,r) row: region -> fp16, rdvec[row] = region.Ws0.
__global__ __launch_bounds__(256) void conv_region(
    const float* __restrict__ region, const float* __restrict__ Ws,
    _Float16* __restrict__ r16, float* __restrict__ rdvec) {
  const long row = blockIdx.x;
  const int tid = threadIdx.x, lane = tid & 63, wid = tid >> 6;
  const long i = row * DD + tid * 4;
  const float4 v = *(const float4*)&region[i];
  half4 h = {(_Float16)v.x, (_Float16)v.y, (_Float16)v.z, (_Float16)v.w};
  *(half4*)&r16[i] = h;
  const float4 w0 = *(const float4*)&Ws[tid * 4];
  float rd = v.x * w0.x + v.y * w0.y + v.z * w0.z + v.w * w0.w;
  rd = wave_sum(rd);
  __shared__ float sm[4];
  if (lane == 0) sm[wid] = rd;
  __syncthreads();
  if (tid == 0) rdvec[row] = sm[0] + sm[1] + sm[2] + sm[3];
}

// One block per (b,t) row: query -> fp16, cvec[row] = q.(Wq br).
__global__ __launch_bounds__(256) void conv_query(
    const float* __restrict__ query, const float* __restrict__ wqbr,
    _Float16* __restrict__ q16, float* __restrict__ cvec) {
  const long row = blockIdx.x;
  const int tid = threadIdx.x, lane = tid & 63, wid = tid >> 6;
  const long i = row * DD + tid * 4;
  const float4 v = *(const float4*)&query[i];
  half4 h = {(_Float16)v.x, (_Float16)v.y, (_Float16)v.z, (_Float16)v.w};
  *(half4*)&q16[i] = h;
  const float4 w = *(const float4*)&wqbr[tid * 4];
  float c = v.x * w.x + v.y * w.y + v.z * w.z + v.w * w.w;
  c = wave_sum(c);
  __shared__ float sm[4];
  if (lane == 0) sm[wid] = c;
  __syncthreads();
  if (tid == 0) cvec[row] = sm[0] + sm[1] + sm[2] + sm[3];
}

// outv[row] = X[row,:] . v  (tiny; wqbr = Wq @ br).
__global__ __launch_bounds__(256) void rowdot(const float* __restrict__ X,
                                              const float* __restrict__ v,
                                              float* __restrict__ outv, int Kk) {
  const int row = blockIdx.x * 4 + (threadIdx.x >> 6);
  const int lane = threadIdx.x & 63;
  const float* x = X + (long)row * Kk;
  float s = 0.f;
  for (int k = lane; k < Kk; k += 64) s += x[k] * v[k];
  s = wave_sum(s);
  if (lane == 0) outv[row] = s;
}

extern "C" void kernel_launch(void* const* d_in, const int* in_sizes, int n_in,
                              void* d_out, int out_size, void* d_ws, size_t ws_size,
                              hipStream_t stream) {
  const float* region = (const float*)d_in[0];
  const float* query  = (const float*)d_in[1];
  const float* Wr     = (const float*)d_in[2];
  const float* br     = (const float*)d_in[3];
  const float* Wq     = (const float*)d_in[4];
  // d_in[5] = bq: t-constant per score row, cancels in softmax.
  const float* Ws     = (const float*)d_in[6];
  const float* bs     = (const float*)d_in[7];
  float* out = (float*)d_out;

  // ws layout (~74 MiB; round-3 used ~104 safely).
  char* p = (char*)d_ws;
  _Float16* region16 = (_Float16*)p;                   // 32 MiB
  _Float16* query16  = (_Float16*)(p + (32u << 20));   // 16 MiB
  _Float16* Qp       = (_Float16*)(p + (48u << 20));   // 16 MiB
  _Float16* Wr16     = (_Float16*)(p + (64u << 20));   // 2 MiB
  _Float16* Wq16     = (_Float16*)(p + (66u << 20));   // 2 MiB
  _Float16* M2       = (_Float16*)(p + (68u << 20));   // 2 MiB
  _Float16* Ws16     = (_Float16*)(p + (70u << 20));   // 4 KiB (Ws1|Ws2)
  float*    wqbr     = (float*)(p + (70u << 20) + 65536);
  float*    cvec     = wqbr + 1024;
  float*    rdvec    = cvec + BD * TD;
  float*    Ms       = (float*)(p + (72u << 20));      // 3 x 512 KiB stats
  float*    Ls       = Ms + 8 * BR;
  float*    Hs       = Ls + 8 * BR;

  cvt_f2h<<<dim3(1024), 256, 0, stream>>>(Wr, Wr16);
  cvt_f2h<<<dim3(1024), 256, 0, stream>>>(Wq, Wq16);
  cvt_f2h<<<dim3(2), 256, 0, stream>>>(Ws + DD, Ws16);
  rowdot<<<dim3(DD / 4), 256, 0, stream>>>(Wq, br, wqbr, DD);
  conv_region<<<dim3(BD * RD), 256, 0, stream>>>(region, Ws, region16, rdvec);
  conv_query<<<dim3(BD * TD), 256, 0, stream>>>(query, wqbr, query16, cvec);

  // M2 = Wr @ Wq^T  [D,D] fp16.
  gemm_pipe<false><<<dim3(8, 8, 1), 256, 0, stream>>>(
      Wr16, Wq16, nullptr, M2, nullptr, nullptr, nullptr, nullptr, nullptr,
      DD, DD, 0, 0, 0);
  // Qp = query @ M2^T  [B*T, D] fp16.
  gemm_pipe<false><<<dim3(8, 64, 1), 256, 0, stream>>>(
      query16, M2, nullptr, Qp, nullptr, nullptr, nullptr, nullptr, nullptr,
      DD, DD, 0, 0, 0);
  // Fused: accS = NT(region,Qp)+cvec, accH = NT(Ws1+region*Ws2, query),
  // split-softmax stats per 64-col chunk.
  gemm_pipe<true><<<dim3(TD / 128, RD / 128, BD), 256, 0, stream>>>(
      region16, Qp, query16, nullptr, Ms, Ls, Hs, cvec, Ws16,
      TD, DD, (long)RD * DD, (long)TD * DD, 0);
  // out = HS/L + region.Ws0 + bs.
  combine<<<dim3(BR / 256), 256, 0, stream>>>(Ms, Ls, Hs, rdvec, bs, out);
}

// Round 5
// 229.281 us; speedup vs baseline: 5.5848x; 1.1314x over previous
//
#include <hip/hip_runtime.h>

// CrossModalAttentionScorer — round 5: 8-wave blocks (16 waves/CU) + XCD remap.
// B=16, R=1024, T=512, D=H=1024.
//
//   M2 = Wr @ Wq^T; Qp = NT(query, M2); cvec = q.(Wq br); bq cancels in softmax.
//   Fused: accS = NT(region,Qp)+cvec, accH = NT(Ws1+region*Ws2, query),
//   split-softmax stats per 64-col chunk; combine -> out.
//
// Round-4 lesson: 2 blocks/CU x 4 waves = 2 waves/SIMD cannot hide miss
// latency (MfmaUtil 20%, Occ 10%). This round: 512-thread blocks under
// __launch_bounds__(512,4) -> 4 waves/SIMD, plus XCD-aware remap so each
// XCD's L2 holds its batch working set (~4 MB).

#define BD 16
#define RD 1024
#define TD 512
#define DD 1024
#define BR (BD * RD)

typedef _Float16 half8 __attribute__((ext_vector_type(8)));
typedef _Float16 half4 __attribute__((ext_vector_type(4)));
typedef float floatx4 __attribute__((ext_vector_type(4)));

__device__ __forceinline__ float wave_sum(float v) {
#pragma unroll
  for (int off = 32; off > 0; off >>= 1) v += __shfl_down(v, off);
  return v;
}

// Pipelined 128x128x32 NT GEMM, 512 threads = 8 waves (4x2), wave = 32x64.
// FUSED: two B tiles (B0=Qp scores, B1=query H) + split-softmax stats.
// remap: 0 = natural, 1 = Qp-style (XCD m-strips), 2 = fused (XCD batch pairs).
template <bool FUSED>
__global__ __launch_bounds__(512, 4) void gemm_pipe(
    const _Float16* __restrict__ A, const _Float16* __restrict__ B0,
    const _Float16* __restrict__ B1, _Float16* __restrict__ C,
    float* __restrict__ Ms, float* __restrict__ Ls, float* __restrict__ Hs,
    const float* __restrict__ cvec, const _Float16* __restrict__ wsh,
    int N, int K, long sA, long sB, long sC, int remap) {
  constexpr int TT = FUSED ? 3 : 2;  // tiles per LDS buffer (A,B0[,B1])
  __shared__ __align__(16) _Float16 lds[2 * TT * 4096];
  __shared__ __align__(16) _Float16 wlds[FUSED ? 2048 : 16];

  const int lin = blockIdx.x + gridDim.x * (blockIdx.y + gridDim.y * blockIdx.z);
  int b, mt, nt;
  if (remap == 2) {          // 512 blocks: XCD s owns batches 2s,2s+1
    const int s = lin & 7, u = lin >> 3;
    b = 2 * s + (u >> 5);
    const int t = u & 31;
    mt = t >> 2; nt = t & 3;
  } else if (remap == 1) {   // 512 blocks: XCD s owns m-strip [8s,8s+8)
    const int s = lin & 7, u = lin >> 3;
    b = 0;
    mt = s * 8 + (u >> 3); nt = u & 7;
  } else {
    b = blockIdx.z; mt = blockIdx.y; nt = blockIdx.x;
  }
  const int m0 = mt * 128, n0 = nt * 128;
  A += (long)b * sA;
  B0 += (long)b * sB;
  if (FUSED) B1 += (long)b * sB;

  const int tid = threadIdx.x, lane = tid & 63, w = tid >> 6;
  const int wr = w >> 1, wc = w & 1;

  // Staging: wave w owns rows 16w..16w+15 of each tile; lane L -> row lrow,
  // LDS chunk slot (L&3), global chunk xor-swizzled (r3-proven: 0 conflicts).
  const int lrow = lane >> 2;                 // 0..15
  const int slot = lane & 3;
  const int scol = (slot ^ ((lrow >> 1) & 3)) * 8;
  const int srow = 16 * w + lrow;             // 0..127
  const _Float16* gA = A + (long)(m0 + srow) * K + scol;
  const _Float16* gP = B0 + (long)(n0 + srow) * K + scol;
  const _Float16* gQ = FUSED ? B1 + (long)(n0 + srow) * K + scol : nullptr;
  const int wofs = srow * 32 + slot * 8;      // halves within a tile

  if (FUSED && tid < 256) *(int4*)&wlds[tid * 8] = *(const int4*)&wsh[tid * 8];

  const int NK = K / 32;
  int4 pA, pP, pQ;
  pA = *(const int4*)gA;
  pP = *(const int4*)gP;
  if (FUSED) pQ = *(const int4*)gQ;
  *(int4*)&lds[wofs] = pA;
  *(int4*)&lds[4096 + wofs] = pP;
  if (FUSED) *(int4*)&lds[8192 + wofs] = pQ;
  if (NK > 1) {
    pA = *(const int4*)(gA + 32);
    pP = *(const int4*)(gP + 32);
    if (FUSED) pQ = *(const int4*)(gQ + 32);
  }
  __syncthreads();

  floatx4 accS[2][4] = {};
  floatx4 accH[2][4] = {};  // dead when !FUSED
  const int fr = lane & 15, g = lane >> 4;
  const int fs = (g ^ ((fr >> 1) & 3)) * 8;

  for (int kt = 0; kt < NK; ++kt) {
    const int cur = (kt & 1) * TT * 4096;
    const int nxt = ((kt + 1) & 1) * TT * 4096;
    if (kt + 1 < NK) {  // stage tile kt+1: regs -> LDS buf nxt
      *(int4*)&lds[nxt + wofs] = pA;
      *(int4*)&lds[nxt + 4096 + wofs] = pP;
      if (FUSED) *(int4*)&lds[nxt + 8192 + wofs] = pQ;
    }
    if (kt + 2 < NK) {  // prefetch tile kt+2 -> regs (full iter in flight)
      const long go = (long)(kt + 2) * 32;
      pA = *(const int4*)(gA + go);
      pP = *(const int4*)(gP + go);
      if (FUSED) pQ = *(const int4*)(gQ + go);
    }
    half8 af[2], bp[4], bq[4], w1f, w2f;
#pragma unroll
    for (int i = 0; i < 2; ++i)
      af[i] = *(const half8*)&lds[cur + (32 * wr + 16 * i + fr) * 32 + fs];
#pragma unroll
    for (int j = 0; j < 4; ++j)
      bp[j] = *(const half8*)&lds[cur + 4096 + (64 * wc + 16 * j + fr) * 32 + fs];
    if (FUSED) {
#pragma unroll
      for (int j = 0; j < 4; ++j)
        bq[j] = *(const half8*)&lds[cur + 8192 + (64 * wc + 16 * j + fr) * 32 + fs];
      w1f = *(const half8*)&wlds[kt * 32 + g * 8];
      w2f = *(const half8*)&wlds[1024 + kt * 32 + g * 8];
    }
#pragma unroll
    for (int i = 0; i < 2; ++i)
#pragma unroll
      for (int j = 0; j < 4; ++j)
        accS[i][j] = __builtin_amdgcn_mfma_f32_16x16x32_f16(af[i], bp[j], accS[i][j], 0, 0, 0);
    if (FUSED) {
#pragma unroll
      for (int i = 0; i < 2; ++i) af[i] = w1f + af[i] * w2f;  // A' for H
#pragma unroll
      for (int i = 0; i < 2; ++i)
#pragma unroll
        for (int j = 0; j < 4; ++j)
          accH[i][j] = __builtin_amdgcn_mfma_f32_16x16x32_f16(af[i], bq[j], accH[i][j], 0, 0, 0);
    }
    __syncthreads();
  }

  // C/D layout: col = lane&15 (=fr), row = g*4 + reg.
  const int cr = g * 4, cc = fr;
  if (!FUSED) {
    _Float16* Cw = C + (long)b * sC;
#pragma unroll
    for (int i = 0; i < 2; ++i)
#pragma unroll
      for (int r = 0; r < 4; ++r)
#pragma unroll
        for (int j = 0; j < 4; ++j)
          Cw[(long)(m0 + 32 * wr + 16 * i + cr + r) * N + n0 + 64 * wc + 16 * j + cc] =
              (_Float16)accS[i][j][r];
  } else {
    float cv[4];
#pragma unroll
    for (int j = 0; j < 4; ++j)
      cv[j] = cvec[(long)b * TD + n0 + 64 * wc + 16 * j + cc];
    const int chunk = nt * 2 + wc;  // 64-col chunk 0..7
    const long rowBase = (long)b * RD + m0 + 32 * wr + cr;
#pragma unroll
    for (int i = 0; i < 2; ++i) {
#pragma unroll
      for (int r = 0; r < 4; ++r) {
        float mx = -1e30f;
#pragma unroll
        for (int j = 0; j < 4; ++j) mx = fmaxf(mx, accS[i][j][r] + cv[j]);
        mx = fmaxf(mx, __shfl_xor(mx, 1));
        mx = fmaxf(mx, __shfl_xor(mx, 2));
        mx = fmaxf(mx, __shfl_xor(mx, 4));
        mx = fmaxf(mx, __shfl_xor(mx, 8));
        float l = 0.f, hs = 0.f;
#pragma unroll
        for (int j = 0; j < 4; ++j) {
          const float e = __expf(accS[i][j][r] + cv[j] - mx);
          l += e;
          hs += e * accH[i][j][r];
        }
        l += __shfl_xor(l, 1); hs += __shfl_xor(hs, 1);
        l += __shfl_xor(l, 2); hs += __shfl_xor(hs, 2);
        l += __shfl_xor(l, 4); hs += __shfl_xor(hs, 4);
        l += __shfl_xor(l, 8); hs += __shfl_xor(hs, 8);
        if (cc == 0) {
          const long idx = (long)chunk * BR + rowBase + 16 * i + r;
          Ms[idx] = mx;
          Ls[idx] = l;
          Hs[idx] = hs;
        }
      }
    }
  }
}

// Combine 8 chunk-stats per row: out = HS/L + rdvec + bs.
__global__ __launch_bounds__(256) void combine(
    const float* __restrict__ Ms, const float* __restrict__ Ls,
    const float* __restrict__ Hs, const float* __restrict__ rdvec,
    const float* __restrict__ bs, float* __restrict__ out) {
  const int row = blockIdx.x * 256 + threadIdx.x;
  float mv[8];
  float gm = -1e30f;
#pragma unroll
  for (int c = 0; c < 8; ++c) {
    mv[c] = Ms[(long)c * BR + row];
    gm = fmaxf(gm, mv[c]);
  }
  float L = 0.f, HS = 0.f;
#pragma unroll
  for (int c = 0; c < 8; ++c) {
    const float s = __expf(mv[c] - gm);
    L += Ls[(long)c * BR + row] * s;
    HS += Hs[(long)c * BR + row] * s;
  }
  out[row] = HS / L + rdvec[row] + bs[0];
}

// prep: blocks [0,1024) Wr->fp16, [1024,2048) Wq->fp16, [2048,2050) Ws1|Ws2,
// [2050,2306) wqbr = Wq @ br.
__global__ __launch_bounds__(256) void prep(
    const float* __restrict__ Wr, const float* __restrict__ Wq,
    const float* __restrict__ Ws, const float* __restrict__ br,
    _Float16* __restrict__ Wr16, _Float16* __restrict__ Wq16,
    _Float16* __restrict__ Ws16, float* __restrict__ wqbr) {
  const int blk = blockIdx.x, tid = threadIdx.x;
  if (blk < 2050) {
    const float* src;
    _Float16* dst;
    long i;
    if (blk < 1024) { src = Wr; dst = Wr16; i = (long)blk * 1024 + tid * 4; }
    else if (blk < 2048) { src = Wq; dst = Wq16; i = (long)(blk - 1024) * 1024 + tid * 4; }
    else { src = Ws + DD; dst = Ws16; i = (long)(blk - 2048) * 1024 + tid * 4; }
    const float4 v = *(const float4*)&src[i];
    half4 h = {(_Float16)v.x, (_Float16)v.y, (_Float16)v.z, (_Float16)v.w};
    *(half4*)&dst[i] = h;
  } else {
    const int row = (blk - 2050) * 4 + (tid >> 6);
    const int lane = tid & 63;
    const float* x = Wq + (long)row * DD;
    float s = 0.f;
    for (int k = lane; k < DD; k += 64) s += x[k] * br[k];
    s = wave_sum(s);
    if (lane == 0) wqbr[row] = s;
  }
}

// One block per (b,r) row: region -> fp16, rdvec[row] = region.Ws0.
__global__ __launch_bounds__(256) void conv_region(
    const float* __restrict__ region, const float* __restrict__ Ws,
    _Float16* __restrict__ r16, float* __restrict__ rdvec) {
  const long row = blockIdx.x;
  const int tid = threadIdx.x, lane = tid & 63, wid = tid >> 6;
  const long i = row * DD + tid * 4;
  const float4 v = *(const float4*)&region[i];
  half4 h = {(_Float16)v.x, (_Float16)v.y, (_Float16)v.z, (_Float16)v.w};
  *(half4*)&r16[i] = h;
  const float4 w0 = *(const float4*)&Ws[tid * 4];
  float rd = v.x * w0.x + v.y * w0.y + v.z * w0.z + v.w * w0.w;
  rd = wave_sum(rd);
  __shared__ float sm[4];
  if (lane == 0) sm[wid] = rd;
  __syncthreads();
  if (tid == 0) rdvec[row] = sm[0] + sm[1] + sm[2] + sm[3];
}

// One block per (b,t) row: query -> fp16, cvec[row] = q.(Wq br).
__global__ __launch_bounds__(256) void conv_query(
    const float* __restrict__ query, const float* __restrict__ wqbr,
    _Float16* __restrict__ q16, float* __restrict__ cvec) {
  const long row = blockIdx.x;
  const int tid = threadIdx.x, lane = tid & 63, wid = tid >> 6;
  const long i = row * DD + tid * 4;
  const float4 v = *(const float4*)&query[i];
  half4 h = {(_Float16)v.x, (_Float16)v.y, (_Float16)v.z, (_Float16)v.w};
  *(half4*)&q16[i] = h;
  const float4 w = *(const float4*)&wqbr[tid * 4];
  float c = v.x * w.x + v.y * w.y + v.z * w.z + v.w * w.w;
  c = wave_sum(c);
  __shared__ float sm[4];
  if (lane == 0) sm[wid] = c;
  __syncthreads();
  if (tid == 0) cvec[row] = sm[0] + sm[1] + sm[2] + sm[3];
}

extern "C" void kernel_launch(void* const* d_in, const int* in_sizes, int n_in,
                              void* d_out, int out_size, void* d_ws, size_t ws_size,
                              hipStream_t stream) {
  const float* region = (const float*)d_in[0];
  const float* query  = (const float*)d_in[1];
  const float* Wr     = (const float*)d_in[2];
  const float* br     = (const float*)d_in[3];
  const float* Wq     = (const float*)d_in[4];
  // d_in[5] = bq: t-constant per score row, cancels in softmax.
  const float* Ws     = (const float*)d_in[6];
  const float* bs     = (const float*)d_in[7];
  float* out = (float*)d_out;

  // ws layout (~74 MiB).
  char* p = (char*)d_ws;
  _Float16* region16 = (_Float16*)p;                   // 32 MiB
  _Float16* query16  = (_Float16*)(p + (32u << 20));   // 16 MiB
  _Float16* Qp       = (_Float16*)(p + (48u << 20));   // 16 MiB
  _Float16* Wr16     = (_Float16*)(p + (64u << 20));   // 2 MiB
  _Float16* Wq16     = (_Float16*)(p + (66u << 20));   // 2 MiB
  _Float16* M2       = (_Float16*)(p + (68u << 20));   // 2 MiB
  _Float16* Ws16     = (_Float16*)(p + (70u << 20));   // 4 KiB (Ws1|Ws2)
  float*    wqbr     = (float*)(p + (70u << 20) + 65536);
  float*    cvec     = wqbr + 1024;
  float*    rdvec    = cvec + BD * TD;
  float*    Ms       = (float*)(p + (72u << 20));      // 3 x 512 KiB stats
  float*    Ls       = Ms + 8 * BR;
  float*    Hs       = Ls + 8 * BR;

  prep<<<dim3(2306), 256, 0, stream>>>(Wr, Wq, Ws, br, Wr16, Wq16, Ws16, wqbr);
  conv_region<<<dim3(BD * RD), 256, 0, stream>>>(region, Ws, region16, rdvec);
  conv_query<<<dim3(BD * TD), 256, 0, stream>>>(query, wqbr, query16, cvec);

  // M2 = Wr @ Wq^T  [D,D] fp16.
  gemm_pipe<false><<<dim3(8, 8, 1), 512, 0, stream>>>(
      Wr16, Wq16, nullptr, M2, nullptr, nullptr, nullptr, nullptr, nullptr,
      DD, DD, 0, 0, 0, 0);
  // Qp = query @ M2^T  [B*T, D] fp16, XCD m-strips.
  gemm_pipe<false><<<dim3(8, 64, 1), 512, 0, stream>>>(
      query16, M2, nullptr, Qp, nullptr, nullptr, nullptr, nullptr, nullptr,
      DD, DD, 0, 0, 0, 1);
  // Fused S/H + split-softmax stats, XCD batch-pairs.
  gemm_pipe<true><<<dim3(TD / 128, RD / 128, BD), 512, 0, stream>>>(
      region16, Qp, query16, nullptr, Ms, Ls, Hs, cvec, Ws16,
      TD, DD, (long)RD * DD, (long)TD * DD, 0, 2);
  // out = HS/L + region.Ws0 + bs.
  combine<<<dim3(BR / 256), 256, 0, stream>>>(Ms, Ls, Hs, rdvec, bs, out);
}